// Round 1
// baseline (1299.186 us; speedup 1.0000x reference)
//
#include <hip/hip_runtime.h>
#include <math.h>

// Problem geometry (fixed by reference):
//   hidden_states [16,64,64,512] fp32 -> A [M=65536, K=512]
//   w_qkv [1536,512], b_qkv [1536]
//   qkv = A @ W^T + b   -> [65536, 1536] fp32 (in d_ws, 402.7 MB)
//   pass 2: scrambled elementwise softmax -> out [16,64,64,512] fp32

// ---------------------------------------------------------------------------
// Kernel 1: fp32 GEMM  C[M,N] = A[M,K] * W[N,K]^T + bias[N]
// BM=BN=128, BK=8, 256 threads, 8x8 outputs/thread.
// ---------------------------------------------------------------------------
__global__ __launch_bounds__(256) void qkv_gemm_f32(
    const float* __restrict__ A,    // [65536,512]
    const float* __restrict__ W,    // [1536,512]
    const float* __restrict__ bias, // [1536]
    float* __restrict__ C)          // [65536,1536]
{
    __shared__ float As[8][128];
    __shared__ float Bs[8][128];

    const int t    = threadIdx.x;
    const int row0 = blockIdx.x * 128;  // 512 blocks
    const int col0 = blockIdx.y * 128;  // 12 blocks
    const int ty   = t >> 4;            // 0..15
    const int tx   = t & 15;            // 0..15
    const int lr   = t >> 1;            // 0..127 (tile row for staging)
    const int lk   = (t & 1) * 4;       // 0 or 4 (k offset for staging)

    const float* Aptr = A + (size_t)(row0 + lr) * 512 + lk;
    const float* Wptr = W + (size_t)(col0 + lr) * 512 + lk;

    float acc[8][8];
#pragma unroll
    for (int i = 0; i < 8; ++i)
#pragma unroll
        for (int j = 0; j < 8; ++j) acc[i][j] = 0.f;

    for (int kb = 0; kb < 512; kb += 8) {
        const float4 av = *reinterpret_cast<const float4*>(Aptr + kb);
        const float4 wv = *reinterpret_cast<const float4*>(Wptr + kb);
        __syncthreads();  // previous iteration's reads done
        As[lk + 0][lr] = av.x; As[lk + 1][lr] = av.y;
        As[lk + 2][lr] = av.z; As[lk + 3][lr] = av.w;
        Bs[lk + 0][lr] = wv.x; Bs[lk + 1][lr] = wv.y;
        Bs[lk + 2][lr] = wv.z; Bs[lk + 3][lr] = wv.w;
        __syncthreads();
#pragma unroll
        for (int kk = 0; kk < 8; ++kk) {
            float a[8], b[8];
            *reinterpret_cast<float4*>(&a[0]) =
                *reinterpret_cast<const float4*>(&As[kk][ty * 8]);
            *reinterpret_cast<float4*>(&a[4]) =
                *reinterpret_cast<const float4*>(&As[kk][ty * 8 + 4]);
            *reinterpret_cast<float4*>(&b[0]) =
                *reinterpret_cast<const float4*>(&Bs[kk][tx * 8]);
            *reinterpret_cast<float4*>(&b[4]) =
                *reinterpret_cast<const float4*>(&Bs[kk][tx * 8 + 4]);
#pragma unroll
            for (int i = 0; i < 8; ++i)
#pragma unroll
                for (int j = 0; j < 8; ++j)
                    acc[i][j] = fmaf(a[i], b[j], acc[i][j]);
        }
    }

    // epilogue: + bias, vector stores
    float bv[8];
#pragma unroll
    for (int j = 0; j < 8; ++j) bv[j] = bias[col0 + tx * 8 + j];

#pragma unroll
    for (int i = 0; i < 8; ++i) {
        const int row = row0 + ty * 8 + i;
        float* Crow = C + (size_t)row * 1536 + col0 + tx * 8;
        float4 o0, o1;
        o0.x = acc[i][0] + bv[0]; o0.y = acc[i][1] + bv[1];
        o0.z = acc[i][2] + bv[2]; o0.w = acc[i][3] + bv[3];
        o1.x = acc[i][4] + bv[4]; o1.y = acc[i][5] + bv[5];
        o1.z = acc[i][6] + bv[6]; o1.w = acc[i][7] + bv[7];
        *reinterpret_cast<float4*>(Crow)     = o0;
        *reinterpret_cast<float4*>(Crow + 4) = o1;
    }
}

// ---------------------------------------------------------------------------
// Kernel 2: scrambled elementwise softmax.
// Block = (b in [0,16), n in [0,8), hw6 in [0,64)); tile = 64 rows x 64 d.
// For row hwlo, d' in [0,64):
//   q  = qkv[b*4096 + hw6*64+hwlo][n*64 + d']
//   k  = qkv[b*4096 + d'*64 + hw6][512 + kn*64 + hwlo],  kn = (n+7)&7
//   s[d'] = 0.125*q*k ; p = softmax(s); out = p[d] * v[d]
//   v  = qkv[b*4096 + hw6*64+hwlo][1024 + kn*64 + d]
// out flat = (((vb*8+(hw6>>3))*64 + ((hw6&7)*8+(hwlo>>3)))*64
//             + ((hwlo&7)*8+n))*512 + fr*64 + d,  vb=b>>3, fr=b&7
// ---------------------------------------------------------------------------
__global__ __launch_bounds__(256) void attn_scramble(
    const float* __restrict__ qkv,  // [65536,1536]
    float* __restrict__ out)        // [16*64*64*512]
{
    __shared__ float Ks[64][65];    // [d'][hwlo], +1 pad

    const int bid = blockIdx.x;     // 0..8191
    const int hw6 = bid & 63;
    const int n   = (bid >> 6) & 7;
    const int b   = bid >> 9;
    const int kn  = (n + 7) & 7;
    const int t   = threadIdx.x;

    // stage K tile: coalesced 64-float rows
    {
        const int hwlo = t & 63;
        const int d0   = t >> 6;  // 0..3
#pragma unroll
        for (int s = 0; s < 16; ++s) {
            const int dp = s * 4 + d0;
            Ks[dp][hwlo] =
                qkv[(size_t)(b * 4096 + dp * 64 + hw6) * 1536 + 512 + kn * 64 + hwlo];
        }
    }
    __syncthreads();

    const int row = t >> 2;  // hwlo for this lane
    const int tl  = t & 3;   // d-quarter: this lane owns d' in [tl*16, tl*16+16)
    const size_t rbase = (size_t)(b * 4096 + hw6 * 64 + row) * 1536;

    float s[16];
    {
        const float* qp = qkv + rbase + n * 64 + tl * 16;
        float q[16];
#pragma unroll
        for (int u = 0; u < 4; ++u)
            *reinterpret_cast<float4*>(&q[u * 4]) =
                *reinterpret_cast<const float4*>(qp + u * 4);
        float m = -1e30f;
#pragma unroll
        for (int u = 0; u < 16; ++u) {
            s[u] = 0.125f * q[u] * Ks[tl * 16 + u][row];
            m = fmaxf(m, s[u]);
        }
        m = fmaxf(m, __shfl_xor(m, 1));
        m = fmaxf(m, __shfl_xor(m, 2));
        float sum = 0.f;
#pragma unroll
        for (int u = 0; u < 16; ++u) {
            s[u] = __expf(s[u] - m);
            sum += s[u];
        }
        sum += __shfl_xor(sum, 1);
        sum += __shfl_xor(sum, 2);
        const float inv = 1.0f / sum;
#pragma unroll
        for (int u = 0; u < 16; ++u) s[u] *= inv;
    }

    const float* vp = qkv + rbase + 1024 + kn * 64 + tl * 16;
    const int vb = b >> 3, fr = b & 7;
    float* op = out +
        ((size_t)(((vb * 8 + (hw6 >> 3)) * 64 + ((hw6 & 7) * 8 + (row >> 3))) * 64 +
                  ((row & 7) * 8 + n)) * 512) + fr * 64 + tl * 16;
#pragma unroll
    for (int u = 0; u < 4; ++u) {
        const float4 v = *reinterpret_cast<const float4*>(vp + u * 4);
        float4 o;
        o.x = s[u * 4 + 0] * v.x;
        o.y = s[u * 4 + 1] * v.y;
        o.z = s[u * 4 + 2] * v.z;
        o.w = s[u * 4 + 3] * v.w;
        *reinterpret_cast<float4*>(op + u * 4) = o;
    }
}

// ---------------------------------------------------------------------------
extern "C" void kernel_launch(void* const* d_in, const int* in_sizes, int n_in,
                              void* d_out, int out_size, void* d_ws, size_t ws_size,
                              hipStream_t stream) {
    const float* hs   = (const float*)d_in[0];  // [16,64,64,512]
    const float* w    = (const float*)d_in[1];  // [1536,512]
    const float* bq   = (const float*)d_in[2];  // [1536]
    float* out = (float*)d_out;
    float* qkv = (float*)d_ws;                  // needs 65536*1536*4 = 402.7 MB

    dim3 g1(512, 12);
    qkv_gemm_f32<<<g1, dim3(256), 0, stream>>>(hs, w, bq, qkv);
    attn_scramble<<<8192, 256, 0, stream>>>(qkv, out);
}

// Round 2
// 1290.808 us; speedup vs baseline: 1.0065x; 1.0065x over previous
//
#include <hip/hip_runtime.h>
#include <math.h>

// Geometry:
//   A = hidden_states [M=65536, K=512] fp32
//   W = w_qkv [N=1536, K=512] fp32, bias [1536]
//   qkv = A @ W^T + bias  -> [65536,1536] fp32 in d_ws
//   pass 2: scrambled elementwise softmax -> out [16,64,64,512] fp32
//
// Fast path: split A,W into bf16 hi/lo, 3-term MFMA GEMM
//   A*W ~= Ah*Wh + Ah*Wl + Al*Wh   (drop Al*Wl ~ 2^-18 relative)

typedef short short8 __attribute__((ext_vector_type(8)));
typedef float f32x4 __attribute__((ext_vector_type(4)));
typedef unsigned short ushort_t;

__device__ __forceinline__ unsigned short f2bf_rne(float f) {
    unsigned u = __float_as_uint(f);
    u += 0x7fffu + ((u >> 16) & 1u);
    return (unsigned short)(u >> 16);
}
__device__ __forceinline__ float bf2f(unsigned short h) {
    return __uint_as_float(((unsigned)h) << 16);
}

__device__ __forceinline__ void gload_lds16(const void* g, void* l) {
    __builtin_amdgcn_global_load_lds(
        (const __attribute__((address_space(1))) unsigned int*)g,
        (__attribute__((address_space(3))) unsigned int*)l, 16, 0, 0);
}

// ---------------------------------------------------------------------------
// Kernel 0: split fp32 -> bf16 hi/lo arrays (same layout as source)
// ---------------------------------------------------------------------------
__global__ __launch_bounds__(256) void split_hi_lo(
    const float* __restrict__ x,
    unsigned short* __restrict__ hi,
    unsigned short* __restrict__ lo,
    int n8)
{
    int idx = blockIdx.x * 256 + threadIdx.x;
    int stride = gridDim.x * 256;
    for (int i = idx; i < n8; i += stride) {
        const float* p = x + (size_t)i * 8;
        float4 a = *reinterpret_cast<const float4*>(p);
        float4 b = *reinterpret_cast<const float4*>(p + 4);
        float v[8] = {a.x, a.y, a.z, a.w, b.x, b.y, b.z, b.w};
        unsigned short h[8], l[8];
#pragma unroll
        for (int j = 0; j < 8; ++j) {
            h[j] = f2bf_rne(v[j]);
            l[j] = f2bf_rne(v[j] - bf2f(h[j]));
        }
        *reinterpret_cast<short8*>(hi + (size_t)i * 8) = *reinterpret_cast<short8*>(h);
        *reinterpret_cast<short8*>(lo + (size_t)i * 8) = *reinterpret_cast<short8*>(l);
    }
}

// ---------------------------------------------------------------------------
// Kernel 1 (fast): 3-term bf16 MFMA GEMM, 128x128 tile, BK=32, 4 waves.
//   C[M=65536,N=1536] = Ah*Wh + Ah*Wl + Al*Wh + bias
// m97-style: linear LDS tiles staged by global_load_lds width=16,
// 2 barriers per K-step.
// ---------------------------------------------------------------------------
__global__ __launch_bounds__(256) void gemm_bf16_3(
    const unsigned short* __restrict__ Ah,
    const unsigned short* __restrict__ Al,
    const unsigned short* __restrict__ Wh,
    const unsigned short* __restrict__ Wl,
    const float* __restrict__ bias,
    float* __restrict__ C)
{
    // 4 tiles of 128x32 bf16 = 8KB each: [Ah|Al|Wh|Wl]
    __shared__ unsigned short lds[4 * 4096];

    // XCD-aware swizzle over 6144 blocks (6144 % 8 == 0)
    const int lin = blockIdx.x + 12 * blockIdx.y;      // grid (12, 512)
    const int swz = (lin & 7) * 768 + (lin >> 3);
    const int col0 = (swz % 12) * 128;
    const int row0 = (swz / 12) * 128;

    const int tid  = threadIdx.x;
    const int wid  = tid >> 6;
    const int lane = tid & 63;
    const int wm   = wid >> 1;   // 0..1
    const int wn   = wid & 1;    // 0..1
    const int l15  = lane & 15;
    const int kq   = lane >> 4;  // 0..3

    // staging role: wave w stages tile w
    const unsigned short* gsrc = (wid == 0) ? Ah : (wid == 1) ? Al
                               : (wid == 2) ? Wh : Wl;
    const int g0 = (wid < 2) ? row0 : col0;
    unsigned short* ldsbase = lds + wid * 4096;
    const int sr = lane >> 2;          // row within 16-row segment
    const int ko = (lane & 3) * 8;     // k offset (8 bf16 = 16B)

    f32x4 acc[4][4];
#pragma unroll
    for (int i = 0; i < 4; ++i)
#pragma unroll
        for (int j = 0; j < 4; ++j) acc[i][j] = (f32x4)0.f;

    const unsigned short* lA_h = lds;
    const unsigned short* lA_l = lds + 4096;
    const unsigned short* lB_h = lds + 8192;
    const unsigned short* lB_l = lds + 12288;

    for (int kb = 0; kb < 512; kb += 32) {
        __syncthreads();  // previous iteration's ds_reads done
#pragma unroll
        for (int s = 0; s < 8; ++s) {
            const unsigned short* gp =
                gsrc + (size_t)(g0 + s * 16 + sr) * 512 + kb + ko;
            gload_lds16(gp, ldsbase + s * 512);
        }
        __syncthreads();  // implies vmcnt(0): LDS tiles ready

        short8 ah[4], bh[4], xl[4];
#pragma unroll
        for (int f = 0; f < 4; ++f) {
            ah[f] = *reinterpret_cast<const short8*>(
                lA_h + (wm * 64 + f * 16 + l15) * 32 + kq * 8);
            bh[f] = *reinterpret_cast<const short8*>(
                lB_h + (wn * 64 + f * 16 + l15) * 32 + kq * 8);
        }
        // term 1: Ah * Wh
#pragma unroll
        for (int mf = 0; mf < 4; ++mf)
#pragma unroll
            for (int nf = 0; nf < 4; ++nf)
                acc[mf][nf] = __builtin_amdgcn_mfma_f32_16x16x32_bf16(
                    ah[mf], bh[nf], acc[mf][nf], 0, 0, 0);
        // term 2: Ah * Wl
#pragma unroll
        for (int f = 0; f < 4; ++f)
            xl[f] = *reinterpret_cast<const short8*>(
                lB_l + (wn * 64 + f * 16 + l15) * 32 + kq * 8);
#pragma unroll
        for (int mf = 0; mf < 4; ++mf)
#pragma unroll
            for (int nf = 0; nf < 4; ++nf)
                acc[mf][nf] = __builtin_amdgcn_mfma_f32_16x16x32_bf16(
                    ah[mf], xl[nf], acc[mf][nf], 0, 0, 0);
        // term 3: Al * Wh
#pragma unroll
        for (int f = 0; f < 4; ++f)
            xl[f] = *reinterpret_cast<const short8*>(
                lA_l + (wm * 64 + f * 16 + l15) * 32 + kq * 8);
#pragma unroll
        for (int mf = 0; mf < 4; ++mf)
#pragma unroll
            for (int nf = 0; nf < 4; ++nf)
                acc[mf][nf] = __builtin_amdgcn_mfma_f32_16x16x32_bf16(
                    xl[mf], bh[nf], acc[mf][nf], 0, 0, 0);
    }

    // epilogue: C/D layout col=lane&15, row=(lane>>4)*4+j
    float bv[4];
#pragma unroll
    for (int nf = 0; nf < 4; ++nf)
        bv[nf] = bias[col0 + wn * 64 + nf * 16 + l15];

#pragma unroll
    for (int mf = 0; mf < 4; ++mf) {
#pragma unroll
        for (int nf = 0; nf < 4; ++nf) {
            const int c = col0 + wn * 64 + nf * 16 + l15;
#pragma unroll
            for (int j = 0; j < 4; ++j) {
                const int r = row0 + wm * 64 + mf * 16 + kq * 4 + j;
                C[(size_t)r * 1536 + c] = acc[mf][nf][j] + bv[nf];
            }
        }
    }
}

// ---------------------------------------------------------------------------
// Kernel 1 (fallback): fp32 VALU GEMM (round-1, known good)
// ---------------------------------------------------------------------------
__global__ __launch_bounds__(256) void qkv_gemm_f32(
    const float* __restrict__ A, const float* __restrict__ W,
    const float* __restrict__ bias, float* __restrict__ C)
{
    __shared__ float As[8][128];
    __shared__ float Bs[8][128];
    const int t = threadIdx.x;
    const int row0 = blockIdx.x * 128, col0 = blockIdx.y * 128;
    const int ty = t >> 4, tx = t & 15;
    const int lr = t >> 1, lk = (t & 1) * 4;
    const float* Aptr = A + (size_t)(row0 + lr) * 512 + lk;
    const float* Wptr = W + (size_t)(col0 + lr) * 512 + lk;
    float acc[8][8];
#pragma unroll
    for (int i = 0; i < 8; ++i)
#pragma unroll
        for (int j = 0; j < 8; ++j) acc[i][j] = 0.f;
    for (int kb = 0; kb < 512; kb += 8) {
        const float4 av = *reinterpret_cast<const float4*>(Aptr + kb);
        const float4 wv = *reinterpret_cast<const float4*>(Wptr + kb);
        __syncthreads();
        As[lk + 0][lr] = av.x; As[lk + 1][lr] = av.y;
        As[lk + 2][lr] = av.z; As[lk + 3][lr] = av.w;
        Bs[lk + 0][lr] = wv.x; Bs[lk + 1][lr] = wv.y;
        Bs[lk + 2][lr] = wv.z; Bs[lk + 3][lr] = wv.w;
        __syncthreads();
#pragma unroll
        for (int kk = 0; kk < 8; ++kk) {
            float a[8], b[8];
            *reinterpret_cast<float4*>(&a[0]) = *reinterpret_cast<const float4*>(&As[kk][ty * 8]);
            *reinterpret_cast<float4*>(&a[4]) = *reinterpret_cast<const float4*>(&As[kk][ty * 8 + 4]);
            *reinterpret_cast<float4*>(&b[0]) = *reinterpret_cast<const float4*>(&Bs[kk][tx * 8]);
            *reinterpret_cast<float4*>(&b[4]) = *reinterpret_cast<const float4*>(&Bs[kk][tx * 8 + 4]);
#pragma unroll
            for (int i = 0; i < 8; ++i)
#pragma unroll
                for (int j = 0; j < 8; ++j)
                    acc[i][j] = fmaf(a[i], b[j], acc[i][j]);
        }
    }
    float bv[8];
#pragma unroll
    for (int j = 0; j < 8; ++j) bv[j] = bias[col0 + tx * 8 + j];
#pragma unroll
    for (int i = 0; i < 8; ++i) {
        const int row = row0 + ty * 8 + i;
        float* Crow = C + (size_t)row * 1536 + col0 + tx * 8;
        float4 o0, o1;
        o0.x = acc[i][0] + bv[0]; o0.y = acc[i][1] + bv[1];
        o0.z = acc[i][2] + bv[2]; o0.w = acc[i][3] + bv[3];
        o1.x = acc[i][4] + bv[4]; o1.y = acc[i][5] + bv[5];
        o1.z = acc[i][6] + bv[6]; o1.w = acc[i][7] + bv[7];
        *reinterpret_cast<float4*>(Crow) = o0;
        *reinterpret_cast<float4*>(Crow + 4) = o1;
    }
}

// ---------------------------------------------------------------------------
// Kernel 2: scrambled elementwise softmax (unchanged, verified round 1)
// ---------------------------------------------------------------------------
__global__ __launch_bounds__(256) void attn_scramble(
    const float* __restrict__ qkv, float* __restrict__ out)
{
    __shared__ float Ks[64][65];
    const int bid = blockIdx.x;
    const int hw6 = bid & 63;
    const int n   = (bid >> 6) & 7;
    const int b   = bid >> 9;
    const int kn  = (n + 7) & 7;
    const int t   = threadIdx.x;
    {
        const int hwlo = t & 63;
        const int d0   = t >> 6;
#pragma unroll
        for (int s = 0; s < 16; ++s) {
            const int dp = s * 4 + d0;
            Ks[dp][hwlo] =
                qkv[(size_t)(b * 4096 + dp * 64 + hw6) * 1536 + 512 + kn * 64 + hwlo];
        }
    }
    __syncthreads();
    const int row = t >> 2;
    const int tl  = t & 3;
    const size_t rbase = (size_t)(b * 4096 + hw6 * 64 + row) * 1536;
    float s[16];
    {
        const float* qp = qkv + rbase + n * 64 + tl * 16;
        float q[16];
#pragma unroll
        for (int u = 0; u < 4; ++u)
            *reinterpret_cast<float4*>(&q[u * 4]) =
                *reinterpret_cast<const float4*>(qp + u * 4);
        float m = -1e30f;
#pragma unroll
        for (int u = 0; u < 16; ++u) {
            s[u] = 0.125f * q[u] * Ks[tl * 16 + u][row];
            m = fmaxf(m, s[u]);
        }
        m = fmaxf(m, __shfl_xor(m, 1));
        m = fmaxf(m, __shfl_xor(m, 2));
        float sum = 0.f;
#pragma unroll
        for (int u = 0; u < 16; ++u) {
            s[u] = __expf(s[u] - m);
            sum += s[u];
        }
        sum += __shfl_xor(sum, 1);
        sum += __shfl_xor(sum, 2);
        const float inv = 1.0f / sum;
#pragma unroll
        for (int u = 0; u < 16; ++u) s[u] *= inv;
    }
    const float* vp = qkv + rbase + 1024 + kn * 64 + tl * 16;
    const int vb = b >> 3, fr = b & 7;
    float* op = out +
        ((size_t)(((vb * 8 + (hw6 >> 3)) * 64 + ((hw6 & 7) * 8 + (row >> 3))) * 64 +
                  ((row & 7) * 8 + n)) * 512) + fr * 64 + tl * 16;
#pragma unroll
    for (int u = 0; u < 4; ++u) {
        const float4 v = *reinterpret_cast<const float4*>(vp + u * 4);
        float4 o;
        o.x = s[u * 4 + 0] * v.x;
        o.y = s[u * 4 + 1] * v.y;
        o.z = s[u * 4 + 2] * v.z;
        o.w = s[u * 4 + 3] * v.w;
        *reinterpret_cast<float4*>(op + u * 4) = o;
    }
}

// ---------------------------------------------------------------------------
extern "C" void kernel_launch(void* const* d_in, const int* in_sizes, int n_in,
                              void* d_out, int out_size, void* d_ws, size_t ws_size,
                              hipStream_t stream) {
    const float* hs = (const float*)d_in[0];  // [65536,512]
    const float* w  = (const float*)d_in[1];  // [1536,512]
    const float* bq = (const float*)d_in[2];  // [1536]
    float* out = (float*)d_out;
    float* qkv = (float*)d_ws;  // 402,653,184 B

    const size_t QKV_B = 402653184ull;
    const size_t AH_B  = 67108864ull;   // 65536*512*2
    const size_t WH_B  = 1572864ull;    // 1536*512*2
    const size_t need  = QKV_B + 2 * AH_B + 2 * WH_B;

    if (ws_size >= need) {
        unsigned short* Ah = (unsigned short*)((char*)d_ws + QKV_B);
        unsigned short* Al = (unsigned short*)((char*)d_ws + QKV_B + AH_B);
        unsigned short* Wh = (unsigned short*)((char*)d_ws + QKV_B + 2 * AH_B);
        unsigned short* Wl = (unsigned short*)((char*)d_ws + QKV_B + 2 * AH_B + WH_B);

        split_hi_lo<<<2048, 256, 0, stream>>>(hs, Ah, Al, 65536 * 512 / 8);
        split_hi_lo<<<384, 256, 0, stream>>>(w, Wh, Wl, 1536 * 512 / 8);
        dim3 g1(12, 512);
        gemm_bf16_3<<<g1, dim3(256), 0, stream>>>(Ah, Al, Wh, Wl, bq, qkv);
    } else {
        dim3 g1(512, 12);
        qkv_gemm_f32<<<g1, dim3(256), 0, stream>>>(hs, w, bq, qkv);
    }
    attn_scramble<<<8192, 256, 0, stream>>>(qkv, out);
}

// Round 3
// 592.418 us; speedup vs baseline: 2.1930x; 2.1789x over previous
//
#include <hip/hip_runtime.h>
#include <math.h>

// Geometry:
//   A = hidden_states [M=65536, K=512] fp32
//   W = w_qkv [N=1536, K=512] fp32, bias [1536]
//   qkv = A @ W^T + bias  -> [65536,1536] fp32 in d_ws (402.7 MB, fits: round 1 ran)
//   pass 2: scrambled elementwise softmax -> out [16,64,64,512] fp32
//
// GEMM: fp32 tiles staged to LDS via global_load_lds (16B, source pre-swizzled),
// bf16 hi/lo trunc-split at fragment-read time, 3-term 16x16x32 bf16 MFMA.

typedef short short8 __attribute__((ext_vector_type(8)));
typedef float f32x4 __attribute__((ext_vector_type(4)));

__device__ __forceinline__ void gload_lds16(const void* g, void* l) {
    __builtin_amdgcn_global_load_lds(
        (const __attribute__((address_space(1))) unsigned int*)g,
        (__attribute__((address_space(3))) unsigned int*)l, 16, 0, 0);
}

// trunc-split 8 fp32 -> bf16 hi + bf16 lo (hi = truncate, lo = exact residual trunc'd)
__device__ __forceinline__ void split8(const f32x4 f0, const f32x4 f1,
                                       short8& hi, short8& lo) {
    float f[8];
#pragma unroll
    for (int j = 0; j < 4; ++j) { f[j] = f0[j]; f[4 + j] = f1[j]; }
    unsigned short h[8], l[8];
#pragma unroll
    for (int j = 0; j < 8; ++j) {
        unsigned u  = __float_as_uint(f[j]);
        unsigned hb = u & 0xffff0000u;
        h[j] = (unsigned short)(hb >> 16);
        float r = f[j] - __uint_as_float(hb);     // exact (Sterbenz)
        l[j] = (unsigned short)(__float_as_uint(r) >> 16);
    }
    hi = *reinterpret_cast<short8*>(h);
    lo = *reinterpret_cast<short8*>(l);
}

// ---------------------------------------------------------------------------
// Kernel 1: C[65536,1536] = A @ W^T + bias.  BM=128, BN=256, BK=32, 512 thr.
// LDS: A tile [128][32] f32 (16KB) @ float 0, W tile [256][32] f32 (32KB) @ 4096.
// 16B chunks stored at kc_lds, holding global chunk kc_lds ^ (row&7).
// ---------------------------------------------------------------------------
__global__ __launch_bounds__(512, 2) void gemm_qkv_mfma(
    const float* __restrict__ A,
    const float* __restrict__ W,
    const float* __restrict__ bias,
    float* __restrict__ C)
{
    __shared__ float lds[12288];   // 48 KB

    // XCD swizzle: 3072 blocks, 8 XCDs, n-fastest so A tile reused in L2
    const int lin = blockIdx.x;
    const int swz = (lin & 7) * 384 + (lin >> 3);
    const int nt = swz % 6, mt = swz / 6;
    const int row0 = mt * 128, col0 = nt * 256;

    const int tid  = threadIdx.x;
    const int wid  = tid >> 6;
    const int lane = tid & 63;
    const int wm   = wid >> 2;   // 0..1
    const int wn   = wid & 3;    // 0..3
    const int l15  = lane & 15;
    const int kq   = lane >> 4;  // 0..3

    // staging: 48 segments of 1KB (64 x 16B chunks); wave w owns s = w*6 + i.
    // chunk c = s*64 + lane; row = c>>3, kc_lds = lane&7, xor = lane>>3 (= row&7).
    const int xo = ((lane & 7) ^ (lane >> 3)) * 4;   // float offset of global chunk
    const float* gp[6];
    float* ldst[6];
#pragma unroll
    for (int i = 0; i < 6; ++i) {
        const int s = wid * 6 + i;
        if (s < 16) {
            gp[i] = A + (size_t)(row0 + s * 8 + (lane >> 3)) * 512 + xo;
        } else {
            gp[i] = W + (size_t)(col0 + (s - 16) * 8 + (lane >> 3)) * 512 + xo;
        }
        ldst[i] = lds + s * 256;   // 1KB per segment
    }

    f32x4 acc[4][4];
#pragma unroll
    for (int i = 0; i < 4; ++i)
#pragma unroll
        for (int j = 0; j < 4; ++j) acc[i][j] = (f32x4)0.f;

    for (int kb = 0; kb < 512; kb += 32) {
        __syncthreads();   // prev iteration's ds_reads done before overwrite
#pragma unroll
        for (int i = 0; i < 6; ++i)
            gload_lds16(gp[i] + kb, ldst[i]);
        __syncthreads();   // drains vmcnt: tiles ready

        // A fragments: rows wm*64 + mf*16 + l15, k = kq*8..+8 (two swizzled 16B)
        short8 ah[4], al[4];
#pragma unroll
        for (int mf = 0; mf < 4; ++mf) {
            const int r = wm * 64 + mf * 16 + l15;
            const f32x4 f0 = *reinterpret_cast<const f32x4*>(
                lds + r * 32 + (((kq * 2 + 0) ^ (r & 7)) << 2));
            const f32x4 f1 = *reinterpret_cast<const f32x4*>(
                lds + r * 32 + (((kq * 2 + 1) ^ (r & 7)) << 2));
            split8(f0, f1, ah[mf], al[mf]);
        }

#pragma unroll
        for (int nf = 0; nf < 4; ++nf) {
            const int r = wn * 64 + nf * 16 + l15;
            const f32x4 g0 = *reinterpret_cast<const f32x4*>(
                lds + 4096 + r * 32 + (((kq * 2 + 0) ^ (r & 7)) << 2));
            const f32x4 g1 = *reinterpret_cast<const f32x4*>(
                lds + 4096 + r * 32 + (((kq * 2 + 1) ^ (r & 7)) << 2));
            short8 wh, wl;
            split8(g0, g1, wh, wl);
#pragma unroll
            for (int mf = 0; mf < 4; ++mf) {
                acc[mf][nf] = __builtin_amdgcn_mfma_f32_16x16x32_bf16(
                    ah[mf], wh, acc[mf][nf], 0, 0, 0);
                acc[mf][nf] = __builtin_amdgcn_mfma_f32_16x16x32_bf16(
                    al[mf], wh, acc[mf][nf], 0, 0, 0);
                acc[mf][nf] = __builtin_amdgcn_mfma_f32_16x16x32_bf16(
                    ah[mf], wl, acc[mf][nf], 0, 0, 0);
            }
        }
    }

    // epilogue: C/D layout col = lane&15, row = (lane>>4)*4 + j
    float bv[4];
#pragma unroll
    for (int nf = 0; nf < 4; ++nf)
        bv[nf] = bias[col0 + wn * 64 + nf * 16 + l15];

#pragma unroll
    for (int mf = 0; mf < 4; ++mf)
#pragma unroll
        for (int nf = 0; nf < 4; ++nf) {
            const int c = col0 + wn * 64 + nf * 16 + l15;
#pragma unroll
            for (int j = 0; j < 4; ++j) {
                const int r = row0 + wm * 64 + mf * 16 + kq * 4 + j;
                C[(size_t)r * 1536 + c] = acc[mf][nf][j] + bv[nf];
            }
        }
}

// ---------------------------------------------------------------------------
// Kernel 2: scrambled elementwise softmax (verified round 1, unchanged)
// ---------------------------------------------------------------------------
__global__ __launch_bounds__(256) void attn_scramble(
    const float* __restrict__ qkv, float* __restrict__ out)
{
    __shared__ float Ks[64][65];
    const int bid = blockIdx.x;
    const int hw6 = bid & 63;
    const int n   = (bid >> 6) & 7;
    const int b   = bid >> 9;
    const int kn  = (n + 7) & 7;
    const int t   = threadIdx.x;
    {
        const int hwlo = t & 63;
        const int d0   = t >> 6;
#pragma unroll
        for (int s = 0; s < 16; ++s) {
            const int dp = s * 4 + d0;
            Ks[dp][hwlo] =
                qkv[(size_t)(b * 4096 + dp * 64 + hw6) * 1536 + 512 + kn * 64 + hwlo];
        }
    }
    __syncthreads();
    const int row = t >> 2;
    const int tl  = t & 3;
    const size_t rbase = (size_t)(b * 4096 + hw6 * 64 + row) * 1536;
    float s[16];
    {
        const float* qp = qkv + rbase + n * 64 + tl * 16;
        float q[16];
#pragma unroll
        for (int u = 0; u < 4; ++u)
            *reinterpret_cast<float4*>(&q[u * 4]) =
                *reinterpret_cast<const float4*>(qp + u * 4);
        float m = -1e30f;
#pragma unroll
        for (int u = 0; u < 16; ++u) {
            s[u] = 0.125f * q[u] * Ks[tl * 16 + u][row];
            m = fmaxf(m, s[u]);
        }
        m = fmaxf(m, __shfl_xor(m, 1));
        m = fmaxf(m, __shfl_xor(m, 2));
        float sum = 0.f;
#pragma unroll
        for (int u = 0; u < 16; ++u) {
            s[u] = __expf(s[u] - m);
            sum += s[u];
        }
        sum += __shfl_xor(sum, 1);
        sum += __shfl_xor(sum, 2);
        const float inv = 1.0f / sum;
#pragma unroll
        for (int u = 0; u < 16; ++u) s[u] *= inv;
    }
    const float* vp = qkv + rbase + 1024 + kn * 64 + tl * 16;
    const int vb = b >> 3, fr = b & 7;
    float* op = out +
        ((size_t)(((vb * 8 + (hw6 >> 3)) * 64 + ((hw6 & 7) * 8 + (row >> 3))) * 64 +
                  ((row & 7) * 8 + n)) * 512) + fr * 64 + tl * 16;
#pragma unroll
    for (int u = 0; u < 4; ++u) {
        const float4 v = *reinterpret_cast<const float4*>(vp + u * 4);
        float4 o;
        o.x = s[u * 4 + 0] * v.x;
        o.y = s[u * 4 + 1] * v.y;
        o.z = s[u * 4 + 2] * v.z;
        o.w = s[u * 4 + 3] * v.w;
        *reinterpret_cast<float4*>(op + u * 4) = o;
    }
}

// ---------------------------------------------------------------------------
extern "C" void kernel_launch(void* const* d_in, const int* in_sizes, int n_in,
                              void* d_out, int out_size, void* d_ws, size_t ws_size,
                              hipStream_t stream) {
    const float* hs = (const float*)d_in[0];  // [65536,512]
    const float* w  = (const float*)d_in[1];  // [1536,512]
    const float* bq = (const float*)d_in[2];  // [1536]
    float* out = (float*)d_out;
    float* qkv = (float*)d_ws;                // 402,653,184 B (known to fit)

    gemm_qkv_mfma<<<3072, 512, 0, stream>>>(hs, w, bq, qkv);
    attn_scramble<<<8192, 256, 0, stream>>>(qkv, out);
}

// Round 4
// 474.626 us; speedup vs baseline: 2.7373x; 1.2482x over previous
//
#include <hip/hip_runtime.h>
#include <math.h>

// Geometry:
//   A = hidden_states [M=65536, K=512] fp32
//   W = w_qkv [N=1536, K=512] fp32, bias [1536]
//   qkv = A @ W^T + bias  -> [65536,1536] fp32 in d_ws
//   pass 2: scrambled elementwise softmax -> out [16,64,64,512] fp32
//
// GEMM: fp16 2-term split-MFMA.  A = Ah + Al (fp16 hi/lo), W -> fp16 (rne).
//   A*W ~= Ah*W + Al*W  (error ~0.5ulp_fp16 per product, absmax ~1.5e-3)
// Split happens ONCE at staging (reg-stage + ds_write), not per fragment read.

typedef _Float16 half8 __attribute__((ext_vector_type(8)));
typedef float f32x4 __attribute__((ext_vector_type(4)));

// split 8 fp32 -> fp16 hi (rne) + fp16 lo (residual)
__device__ __forceinline__ void cvt8(const float4 x, const float4 y,
                                     half8& h, half8& l) {
    const float f[8] = {x.x, x.y, x.z, x.w, y.x, y.y, y.z, y.w};
#pragma unroll
    for (int j = 0; j < 8; ++j) {
        _Float16 hh = (_Float16)f[j];
        h[j] = hh;
        l[j] = (_Float16)(f[j] - (float)hh);
    }
}
__device__ __forceinline__ half8 cvt8s(const float4 x, const float4 y) {
    const float f[8] = {x.x, x.y, x.z, x.w, y.x, y.y, y.z, y.w};
    half8 r;
#pragma unroll
    for (int j = 0; j < 8; ++j) r[j] = (_Float16)f[j];
    return r;
}

// ---------------------------------------------------------------------------
// Kernel 1: C[65536,1536] = A @ W^T + bias.
// BM=BN=128, BK=32, 256 threads (2x2 waves, 64x64/wave), LDS double-buffered.
// Per buffer (halfword offsets): Ah [0,4096), Al [4096,8192), Wh [8192,12288).
// Row = 32 fp16 = 4 chunks of 16B; chunk c stored at phys c ^ ((row>>1)&1)
// -> uniform 8-lane/bank-group (the b128 floor) on both ds_write and ds_read.
// ---------------------------------------------------------------------------
__global__ __launch_bounds__(256, 3) void gemm_qkv_f16x2(
    const float* __restrict__ A,
    const float* __restrict__ W,
    const float* __restrict__ bias,
    float* __restrict__ C)
{
    __shared__ __align__(16) _Float16 lds[24576];   // 48 KB (2 x 24 KB)

    // XCD swizzle: 6144 blocks (%8==0), n-fastest within an XCD for A reuse
    const int lin = blockIdx.x;
    const int swz = (lin & 7) * 768 + (lin >> 3);
    const int nt = swz % 12, mt = swz / 12;
    const int row0 = mt * 128, col0 = nt * 128;

    const int tid  = threadIdx.x;
    const int wid  = tid >> 6;
    const int lane = tid & 63;
    const int wm   = wid >> 1;    // 0..1
    const int wn   = wid & 1;     // 0..1
    const int l15  = lane & 15;
    const int kq   = lane >> 4;   // 0..3

    // staging: thread t covers row ra = t>>1 (A row and W row), k = kh..kh+15
    const int ra = tid >> 1;
    const int kh = (tid & 1) * 16;
    const float* Ag = A + (size_t)(row0 + ra) * 512 + kh;
    const float* Wg = W + (size_t)(col0 + ra) * 512 + kh;
    const int rs  = (ra >> 1) & 1;             // row swizzle bit
    const int wc0 = (((kh >> 3) + 0) ^ rs) * 8;
    const int wc1 = (((kh >> 3) + 1) ^ rs) * 8;

    f32x4 acc[4][4];
#pragma unroll
    for (int i = 0; i < 4; ++i)
#pragma unroll
        for (int j = 0; j < 4; ++j) acc[i][j] = (f32x4)0.f;

    float4 ar[4], wr[4];
#pragma unroll
    for (int u = 0; u < 4; ++u) {
        ar[u] = *reinterpret_cast<const float4*>(Ag + u * 4);
        wr[u] = *reinterpret_cast<const float4*>(Wg + u * 4);
    }

    for (int it = 0; it < 16; ++it) {
        _Float16* bp = lds + (it & 1) * 12288;
        // convert once, write fp16 tiles
        half8 h0, l0, h1, l1;
        cvt8(ar[0], ar[1], h0, l0);
        cvt8(ar[2], ar[3], h1, l1);
        const half8 wv0 = cvt8s(wr[0], wr[1]);
        const half8 wv1 = cvt8s(wr[2], wr[3]);
        *reinterpret_cast<half8*>(bp + ra * 32 + wc0)        = h0;
        *reinterpret_cast<half8*>(bp + ra * 32 + wc1)        = h1;
        *reinterpret_cast<half8*>(bp + 4096 + ra * 32 + wc0) = l0;
        *reinterpret_cast<half8*>(bp + 4096 + ra * 32 + wc1) = l1;
        *reinterpret_cast<half8*>(bp + 8192 + ra * 32 + wc0) = wv0;
        *reinterpret_cast<half8*>(bp + 8192 + ra * 32 + wc1) = wv1;
        __syncthreads();   // single barrier per K-step (double-buffered)

        // prefetch next K-tile into regs (hidden under MFMA phase)
        if (it < 15) {
            const int kb = (it + 1) * 32;
#pragma unroll
            for (int u = 0; u < 4; ++u) {
                ar[u] = *reinterpret_cast<const float4*>(Ag + kb + u * 4);
                wr[u] = *reinterpret_cast<const float4*>(Wg + kb + u * 4);
            }
        }

        // compute from buf[it&1]
        const _Float16* cp = lds + (it & 1) * 12288;
        half8 ah[4], al[4];
#pragma unroll
        for (int mf = 0; mf < 4; ++mf) {
            const int r  = wm * 64 + mf * 16 + l15;
            const int ph = (kq ^ ((r >> 1) & 1)) * 8;
            ah[mf] = *reinterpret_cast<const half8*>(cp + r * 32 + ph);
            al[mf] = *reinterpret_cast<const half8*>(cp + 4096 + r * 32 + ph);
        }
#pragma unroll
        for (int nf = 0; nf < 4; ++nf) {
            const int rb = wn * 64 + nf * 16 + l15;
            const int ph = (kq ^ ((rb >> 1) & 1)) * 8;
            const half8 wv = *reinterpret_cast<const half8*>(cp + 8192 + rb * 32 + ph);
#pragma unroll
            for (int mf = 0; mf < 4; ++mf) {
                acc[mf][nf] = __builtin_amdgcn_mfma_f32_16x16x32_f16(
                    ah[mf], wv, acc[mf][nf], 0, 0, 0);
                acc[mf][nf] = __builtin_amdgcn_mfma_f32_16x16x32_f16(
                    al[mf], wv, acc[mf][nf], 0, 0, 0);
            }
        }
    }

    // epilogue: C/D layout col = lane&15, row = (lane>>4)*4 + j (verified r3)
    float bv[4];
#pragma unroll
    for (int nf = 0; nf < 4; ++nf)
        bv[nf] = bias[col0 + wn * 64 + nf * 16 + l15];

#pragma unroll
    for (int mf = 0; mf < 4; ++mf)
#pragma unroll
        for (int nf = 0; nf < 4; ++nf) {
            const int c = col0 + wn * 64 + nf * 16 + l15;
#pragma unroll
            for (int j = 0; j < 4; ++j) {
                const int r = row0 + wm * 64 + mf * 16 + kq * 4 + j;
                C[(size_t)r * 1536 + c] = acc[mf][nf][j] + bv[nf];
            }
        }
}

// ---------------------------------------------------------------------------
// Kernel 2: scrambled elementwise softmax (verified round 1, unchanged)
// ---------------------------------------------------------------------------
__global__ __launch_bounds__(256) void attn_scramble(
    const float* __restrict__ qkv, float* __restrict__ out)
{
    __shared__ float Ks[64][65];
    const int bid = blockIdx.x;
    const int hw6 = bid & 63;
    const int n   = (bid >> 6) & 7;
    const int b   = bid >> 9;
    const int kn  = (n + 7) & 7;
    const int t   = threadIdx.x;
    {
        const int hwlo = t & 63;
        const int d0   = t >> 6;
#pragma unroll
        for (int s = 0; s < 16; ++s) {
            const int dp = s * 4 + d0;
            Ks[dp][hwlo] =
                qkv[(size_t)(b * 4096 + dp * 64 + hw6) * 1536 + 512 + kn * 64 + hwlo];
        }
    }
    __syncthreads();
    const int row = t >> 2;
    const int tl  = t & 3;
    const size_t rbase = (size_t)(b * 4096 + hw6 * 64 + row) * 1536;
    float s[16];
    {
        const float* qp = qkv + rbase + n * 64 + tl * 16;
        float q[16];
#pragma unroll
        for (int u = 0; u < 4; ++u)
            *reinterpret_cast<float4*>(&q[u * 4]) =
                *reinterpret_cast<const float4*>(qp + u * 4);
        float m = -1e30f;
#pragma unroll
        for (int u = 0; u < 16; ++u) {
            s[u] = 0.125f * q[u] * Ks[tl * 16 + u][row];
            m = fmaxf(m, s[u]);
        }
        m = fmaxf(m, __shfl_xor(m, 1));
        m = fmaxf(m, __shfl_xor(m, 2));
        float sum = 0.f;
#pragma unroll
        for (int u = 0; u < 16; ++u) {
            s[u] = __expf(s[u] - m);
            sum += s[u];
        }
        sum += __shfl_xor(sum, 1);
        sum += __shfl_xor(sum, 2);
        const float inv = 1.0f / sum;
#pragma unroll
        for (int u = 0; u < 16; ++u) s[u] *= inv;
    }
    const float* vp = qkv + rbase + 1024 + kn * 64 + tl * 16;
    const int vb = b >> 3, fr = b & 7;
    float* op = out +
        ((size_t)(((vb * 8 + (hw6 >> 3)) * 64 + ((hw6 & 7) * 8 + (row >> 3))) * 64 +
                  ((row & 7) * 8 + n)) * 512) + fr * 64 + tl * 16;
#pragma unroll
    for (int u = 0; u < 4; ++u) {
        const float4 v = *reinterpret_cast<const float4*>(vp + u * 4);
        float4 o;
        o.x = s[u * 4 + 0] * v.x;
        o.y = s[u * 4 + 1] * v.y;
        o.z = s[u * 4 + 2] * v.z;
        o.w = s[u * 4 + 3] * v.w;
        *reinterpret_cast<float4*>(op + u * 4) = o;
    }
}

// ---------------------------------------------------------------------------
extern "C" void kernel_launch(void* const* d_in, const int* in_sizes, int n_in,
                              void* d_out, int out_size, void* d_ws, size_t ws_size,
                              hipStream_t stream) {
    const float* hs = (const float*)d_in[0];  // [65536,512]
    const float* w  = (const float*)d_in[1];  // [1536,512]
    const float* bq = (const float*)d_in[2];  // [1536]
    float* out = (float*)d_out;
    float* qkv = (float*)d_ws;                // 402,653,184 B (fits: r1/r3 ran)

    gemm_qkv_f16x2<<<6144, 256, 0, stream>>>(hs, w, bq, qkv);
    attn_scramble<<<8192, 256, 0, stream>>>(qkv, out);
}